// Round 7
// baseline (545.922 us; speedup 1.0000x reference)
//
#include <hip/hip_runtime.h>

#define BB 32
#define NN 4096
#define CC 256
#define KK 64
#define DD 256

// ---- workspace layout (in floats) ----
#define VP_OFF   ((size_t)0)                       // vpart   [B][16][K][C]
#define SP_OFF   (VP_OFF  + (size_t)BB*16*KK*CC)   // spart   [B][16][K]
#define VN_OFF   (SP_OFF  + (size_t)BB*16*KK)      // vladn   [B][K*C]
#define O1P_OFF  (VN_OFF  + (size_t)BB*KK*CC)      // o1p     [8][32][256]
#define K5_OFF   (O1P_OFF + (size_t)8*BB*DD)       // k5part  [256][32][256]

// ============================================================
// K1: FUSED  norm + logits + softmax + VLAD partial GEMM
// block = 256 thr; 256 tokens (8 tiles of 32); grid = B*16 = 512
// conv_w resident in LDS; x staged per tile (double-buffered);
// xn never materialized (inv folded into logits and a-weights);
// vlad 8k x 8c register accumulators across the whole chunk.
// LDS ~143 KB -> 1 block/CU, 4 waves.
// ============================================================
__global__ __launch_bounds__(256) void k_fused(
    const float* __restrict__ x, const float* __restrict__ conv_w,
    float* __restrict__ vpart, float* __restrict__ spart) {
  __shared__ __align__(16) float W_lds[64][260];    // 66.6 KB
  __shared__ __align__(16) float xs[2][32][260];    // 66.6 KB (raw x)
  __shared__ __align__(16) float a_tile[32][68];    //  8.7 KB (a * inv)
  __shared__ float mxb[8][36], smb[8][36];
  __shared__ float invls[2][32];

  const int tid = threadIdx.x;
  const int b  = blockIdx.x >> 4;
  const int ch = blockIdx.x & 15;

  // ---- prologue: conv_w -> LDS (once) ----
  {
    const int wr = tid >> 2, wsg = tid & 3;
    const float4* wp = reinterpret_cast<const float4*>(conv_w + (size_t)wr * CC);
#pragma unroll
    for (int j = 0; j < 16; ++j) {
      float4 v = wp[wsg + 4 * j];
      *reinterpret_cast<float4*>(&W_lds[wr][(wsg + 4 * j) * 4]) = v;
    }
  }

  // roles
  const int srow = tid >> 3, sseg = tid & 7;   // staging: 32 rows x 8 segs
  const int tg = tid & 31, kg = tid >> 5;      // compute: token/c-group x k-group

  const float* xbase = x + ((size_t)b * NN + ch * 256) * CC;

  float vacc[8][8];
#pragma unroll
  for (int i = 0; i < 8; ++i)
#pragma unroll
    for (int j = 0; j < 8; ++j) vacc[i][j] = 0.f;
  float ssum[8];
#pragma unroll
  for (int i = 0; i < 8; ++i) ssum[i] = 0.f;

  // full row slice: 8 float4s/thread  (sseg+8j covers 0..63 -> cols 0..255)
  float4 xr4[8];
#define LOADT(t)                                                            \
  {                                                                         \
    const float4* xp = reinterpret_cast<const float4*>(                     \
        xbase + ((size_t)(t) * 32 + srow) * CC);                            \
    _Pragma("unroll")                                                       \
    for (int j = 0; j < 8; ++j) xr4[j] = xp[sseg + 8 * j];                  \
  }
#define STORET(bf)                                                          \
  {                                                                         \
    float q = 0.f;                                                          \
    _Pragma("unroll")                                                       \
    for (int j = 0; j < 8; ++j) {                                           \
      float4 v = xr4[j];                                                    \
      q += v.x * v.x + v.y * v.y + v.z * v.z + v.w * v.w;                   \
      *reinterpret_cast<float4*>(&xs[bf][srow][(sseg + 8 * j) * 4]) = v;    \
    }                                                                       \
    q += __shfl_xor(q, 1); q += __shfl_xor(q, 2); q += __shfl_xor(q, 4);    \
    if (sseg == 0) invls[bf][srow] = 1.0f / fmaxf(sqrtf(q), 1e-12f);        \
  }

  LOADT(0);
  STORET(0);

  for (int t = 0; t < 8; ++t) {
    const int buf = t & 1;
    __syncthreads();   // xs[buf]/invls[buf] visible; prev readers done

    // issue next tile's global loads (land during logits GEMM)
    if (t < 7) LOADT(t + 1);

    // ---- logits GEMM: token tg, k in [kg*8, kg*8+8) ----
    float lg[8];
#pragma unroll
    for (int i = 0; i < 8; ++i) lg[i] = 0.f;
#pragma unroll 4
    for (int c4 = 0; c4 < 64; ++c4) {
      float4 xv = *reinterpret_cast<const float4*>(&xs[buf][tg][c4 * 4]);
#pragma unroll
      for (int i = 0; i < 8; ++i) {
        float4 wv = *reinterpret_cast<const float4*>(&W_lds[kg * 8 + i][c4 * 4]);
        lg[i] = fmaf(xv.x, wv.x,
                fmaf(xv.y, wv.y, fmaf(xv.z, wv.z, fmaf(xv.w, wv.w, lg[i]))));
      }
    }
    const float inv_t = invls[buf][tg];
    float mloc = -3.4e38f;
#pragma unroll
    for (int i = 0; i < 8; ++i) {
      lg[i] *= inv_t;
      mloc = fmaxf(mloc, lg[i]);
    }
    mxb[kg][tg] = mloc;
    __syncthreads();   // mxb visible; also all xr4 loads landed

    // stage next tile (overlaps softmax finish)
    if (t < 7) STORET(buf ^ 1);

    float M = mxb[0][tg];
#pragma unroll
    for (int kk = 1; kk < 8; ++kk) M = fmaxf(M, mxb[kk][tg]);
    float sloc = 0.f;
#pragma unroll
    for (int i = 0; i < 8; ++i) {
      lg[i] = __expf(lg[i] - M);
      sloc += lg[i];
    }
    smb[kg][tg] = sloc;
    __syncthreads();
    float S = smb[0][tg];
#pragma unroll
    for (int kk = 1; kk < 8; ++kk) S += smb[kk][tg];
    const float rs = 1.0f / S;
#pragma unroll
    for (int i = 0; i < 8; ++i) ssum[i] += lg[i] * rs;   // plain a
    const float ai = rs * inv_t;                          // a' = a*inv
    {
      float4 a0 = {lg[0] * ai, lg[1] * ai, lg[2] * ai, lg[3] * ai};
      float4 a1 = {lg[4] * ai, lg[5] * ai, lg[6] * ai, lg[7] * ai};
      *reinterpret_cast<float4*>(&a_tile[tg][kg * 8]) = a0;
      *reinterpret_cast<float4*>(&a_tile[tg][kg * 8 + 4]) = a1;
    }
    __syncthreads();   // a_tile visible

    // ---- VLAD GEMM: k = kg*8+i, c = tg*8+j ----
#pragma unroll 2
    for (int n = 0; n < 32; ++n) {
      float4 a0 = *reinterpret_cast<const float4*>(&a_tile[n][kg * 8]);
      float4 a1 = *reinterpret_cast<const float4*>(&a_tile[n][kg * 8 + 4]);
      float4 x0 = *reinterpret_cast<const float4*>(&xs[buf][n][tg * 8]);
      float4 x1 = *reinterpret_cast<const float4*>(&xs[buf][n][tg * 8 + 4]);
      float av[8] = {a0.x, a0.y, a0.z, a0.w, a1.x, a1.y, a1.z, a1.w};
      float xv[8] = {x0.x, x0.y, x0.z, x0.w, x1.x, x1.y, x1.z, x1.w};
#pragma unroll
      for (int i = 0; i < 8; ++i)
#pragma unroll
        for (int j = 0; j < 8; ++j)
          vacc[i][j] = fmaf(av[i], xv[j], vacc[i][j]);
    }
  }

  // ---- epilogue ----
  const size_t obase = (((size_t)b * 16 + ch) * KK + kg * 8) * CC + tg * 8;
#pragma unroll
  for (int i = 0; i < 8; ++i) {
    float4 o0 = {vacc[i][0], vacc[i][1], vacc[i][2], vacc[i][3]};
    float4 o1 = {vacc[i][4], vacc[i][5], vacc[i][6], vacc[i][7]};
    *reinterpret_cast<float4*>(vpart + obase + (size_t)i * CC) = o0;
    *reinterpret_cast<float4*>(vpart + obase + (size_t)i * CC + 4) = o1;
  }
  // spart: reduce ssum over the 32 token-lanes
#pragma unroll
  for (int i = 0; i < 8; ++i) {
    float s = ssum[i];
    s += __shfl_xor(s, 1); s += __shfl_xor(s, 2); s += __shfl_xor(s, 4);
    s += __shfl_xor(s, 8); s += __shfl_xor(s, 16);
    if (tg == 0) spart[((size_t)b * 16 + ch) * KK + kg * 8 + i] = s;
  }
#undef LOADT
#undef STORET
}

// ============================================================
// K4: reduce partials, subtract S*centroid, intra-norm, /8
// ============================================================
__global__ __launch_bounds__(256) void k_vladnorm(
    const float* __restrict__ vpart, const float* __restrict__ spart,
    const float* __restrict__ cent, float* __restrict__ vladn) {
  const int b = blockIdx.x >> 6, k = blockIdx.x & 63;
  const int c = threadIdx.x;
  float v = 0.f, S = 0.f;
#pragma unroll
  for (int ch = 0; ch < 16; ++ch) {
    v += vpart[(((size_t)b * 16 + ch) * KK + k) * CC + c];
    S += spart[((size_t)b * 16 + ch) * KK + k];
  }
  v -= S * cent[k * CC + c];

  float ssq = v * v;
#pragma unroll
  for (int off = 32; off >= 1; off >>= 1) ssq += __shfl_xor(ssq, off);
  __shared__ float w4[4];
  if ((threadIdx.x & 63) == 0) w4[threadIdx.x >> 6] = ssq;
  __syncthreads();
  const float tot = w4[0] + w4[1] + w4[2] + w4[3];
  const float sc = 0.125f / fmaxf(sqrtf(tot), 1e-12f);
  vladn[(size_t)b * (KK * CC) + k * CC + c] = v * sc;
}

// ============================================================
// K5: hidden GEMM partials. grid (128 islabs, 2 d-halves)
// ============================================================
__global__ __launch_bounds__(256) void k_hidden(
    const float* __restrict__ vladn, const float* __restrict__ hw,
    float* __restrict__ k5p) {
  const int islab = blockIdx.x;           // 0..127
  const int dh = blockIdx.y;              // 0..1
  const int tid = threadIdx.x;
  const int d = dh * 128 + (tid & 127);
  const int ig = tid >> 7;
  const int ibase = islab * 128 + ig * 64;
  const int p = islab * 2 + ig;

  float w[64];
#pragma unroll 8
  for (int ii = 0; ii < 64; ++ii)
    w[ii] = hw[(size_t)(ibase + ii) * DD + d];

#pragma unroll 4
  for (int b2 = 0; b2 < 32; ++b2) {
    const float4* vp = reinterpret_cast<const float4*>(
        vladn + (size_t)b2 * (KK * CC) + ibase);
    float a = 0.f;
#pragma unroll
    for (int q = 0; q < 16; ++q) {
      float4 v = vp[q];
      a = fmaf(v.x, w[q * 4 + 0], a);
      a = fmaf(v.y, w[q * 4 + 1], a);
      a = fmaf(v.z, w[q * 4 + 2], a);
      a = fmaf(v.w, w[q * 4 + 3], a);
    }
    k5p[((size_t)p * 32 + b2) * DD + d] = a;
  }
}

// ============================================================
// K6: reduce 256 hidden partials -> o1p[8][32][256]
// ============================================================
__global__ __launch_bounds__(256) void k_red1(
    const float* __restrict__ k5p, float* __restrict__ o1p) {
  const int b = blockIdx.x & 31, ch = blockIdx.x >> 5, d = threadIdx.x;
  float s = 0.f;
#pragma unroll 4
  for (int p = ch * 32; p < ch * 32 + 32; ++p)
    s += k5p[((size_t)p * 32 + b) * DD + d];
  o1p[((size_t)ch * 32 + b) * DD + d] = s;
}

// ============================================================
// K7: BN -> gating GEMM -> BN -> sigmoid -> multiply
// ============================================================
__global__ __launch_bounds__(256) void k_final(
    const float* __restrict__ o1p, const float* __restrict__ gw,
    const float* __restrict__ bn2g, const float* __restrict__ bn2b,
    const float* __restrict__ gbng, const float* __restrict__ gbnb,
    float* __restrict__ out) {
  __shared__ float yls[32][257];
  __shared__ float gls[32 * 9];
  const int tid = threadIdx.x;

  {
    const int d = tid;
    float vals[32];
    float m = 0.f;
#pragma unroll
    for (int b5 = 0; b5 < 32; ++b5) {
      float v = 0.f;
#pragma unroll
      for (int c2 = 0; c2 < 8; ++c2) v += o1p[((size_t)c2 * 32 + b5) * DD + d];
      vals[b5] = v; m += v;
    }
    m *= (1.f / 32.f);
    float var = 0.f;
#pragma unroll
    for (int b5 = 0; b5 < 32; ++b5) { float tt = vals[b5] - m; var += tt * tt; }
    var *= (1.f / 32.f);
    const float sc = bn2g[d] / sqrtf(var + 1e-5f);
    const float sh = bn2b[d];
#pragma unroll
    for (int b5 = 0; b5 < 32; ++b5) yls[b5][d] = (vals[b5] - m) * sc + sh;
  }
  __syncthreads();

  const int d2t = tid & 7, b4 = tid >> 3;
  const int d2 = blockIdx.x * 8 + d2t;
  float a = 0.f;
  for (int dd = 0; dd < 256; ++dd) a = fmaf(yls[b4][dd], gw[dd * DD + d2], a);
  gls[b4 * 9 + d2t] = a;
  __syncthreads();

  float m2 = 0.f;
#pragma unroll
  for (int b5 = 0; b5 < 32; ++b5) m2 += gls[b5 * 9 + d2t];
  m2 *= (1.f / 32.f);
  float v2 = 0.f;
#pragma unroll
  for (int b5 = 0; b5 < 32; ++b5) { float tt = gls[b5 * 9 + d2t] - m2; v2 += tt * tt; }
  v2 *= (1.f / 32.f);
  const float gn = (a - m2) / sqrtf(v2 + 1e-5f) * gbng[d2] + gbnb[d2];
  const float gate = 1.f / (1.f + __expf(-gn));
  out[b4 * DD + d2] = yls[b4][d2] * gate;
}

// ============================================================
extern "C" void kernel_launch(void* const* d_in, const int* in_sizes, int n_in,
                              void* d_out, int out_size, void* d_ws, size_t ws_size,
                              hipStream_t stream) {
  const float* x      = (const float*)d_in[0];
  const float* conv_w = (const float*)d_in[1];
  const float* cent   = (const float*)d_in[2];
  const float* hw     = (const float*)d_in[3];
  const float* gw     = (const float*)d_in[4];
  const float* bn2g   = (const float*)d_in[5];
  const float* bn2b   = (const float*)d_in[6];
  const float* gbng   = (const float*)d_in[7];
  const float* gbnb   = (const float*)d_in[8];

  float* ws    = (float*)d_ws;
  float* vpart = ws + VP_OFF;
  float* spart = ws + SP_OFF;
  float* vladn = ws + VN_OFF;
  float* o1p   = ws + O1P_OFF;
  float* k5p   = ws + K5_OFF;

  k_fused<<<BB * 16, 256, 0, stream>>>(x, conv_w, vpart, spart);
  k_vladnorm<<<BB * KK, 256, 0, stream>>>(vpart, spart, cent, vladn);
  k_hidden<<<dim3(128, 2), 256, 0, stream>>>(vladn, hw, k5p);
  k_red1<<<256, 256, 0, stream>>>(k5p, o1p);
  k_final<<<32, 256, 0, stream>>>(o1p, gw, bn2g, bn2b, gbng, gbnb,
                                  (float*)d_out);
}

// Round 8
// 377.805 us; speedup vs baseline: 1.4450x; 1.4450x over previous
//
#include <hip/hip_runtime.h>

#define BB 32
#define NN 4096
#define CC 256
#define KK 64
#define DD 256

// ---- workspace layout (in floats) ----
#define SA_OFF   ((size_t)0)                       // sa      [B][K][N]
#define INV_OFF  (SA_OFF  + (size_t)BB*KK*NN)      // invn    [B][N]
#define VP_OFF   (INV_OFF + (size_t)BB*NN)         // vpart   [B][16][K][C]
#define SP_OFF   (VP_OFF  + (size_t)BB*16*KK*CC)   // spart   [B][16][K]
#define VN_OFF   (SP_OFF  + (size_t)BB*16*KK)      // vladn   [B][K*C]
#define O1P_OFF  (VN_OFF  + (size_t)BB*KK*CC)      // o1p     [8][32][256]
#define K5_OFF   (O1P_OFF + (size_t)8*BB*DD)       // k5part  [256][32][256]
#define Z_OFF    (K5_OFF  + (size_t)256*BB*DD)     // z       [32][256]

// ============================================================
// K1: per-token L2 norm + logits + softmax over K
// block = 256 thr; 128 tokens/block; grid = B * N/128 = 1024
// LDS ~31 KB -> 5 blocks/CU cap, 4 resident (grid) = 16 waves/CU.
// ============================================================
__global__ __launch_bounds__(256) void k_softmax(
    const float* __restrict__ x, const float* __restrict__ conv_w,
    float* __restrict__ sa, float* __restrict__ invn) {
  __shared__ __align__(16) float xs[16][136];    // chunk of x, [c][t]
  __shared__ __align__(16) float wls[16][72];    // chunk of W, [c][k]
  __shared__ float mxb[16][132], smb[16][132];   // padded: kg-stride conflict-free
  __shared__ float invls[128];

  const int tid = threadIdx.x;
  const int b  = blockIdx.x >> 5;
  const int n0 = (blockIdx.x & 31) * 128;

  const int r = tid >> 1, s = tid & 1;        // x staging: 128 rows x 2 segs
  const int wk = tid >> 2, wsg = tid & 3;     // W staging: 64 k x 4 segs
  const int tg = tid & 15, kg = tid >> 4;     // compute: 16 tok-grp x 16 k-grp

  const float4* xrow = reinterpret_cast<const float4*>(
      x + ((size_t)b * NN + n0 + r) * CC);
  const float4* wrow = reinterpret_cast<const float4*>(conv_w + (size_t)wk * CC);

  float acc[8][4];
#pragma unroll
  for (int i = 0; i < 8; ++i)
#pragma unroll
    for (int j = 0; j < 4; ++j) acc[i][j] = 0.f;
  float ssq = 0.f;

  float4 xr[2], wr;
  xr[0] = xrow[s * 2]; xr[1] = xrow[s * 2 + 1];
  wr = wrow[wsg];

  for (int ch = 0; ch < 16; ++ch) {
    __syncthreads();   // previous chunk's readers done
#pragma unroll
    for (int j = 0; j < 2; ++j) {
      float4 v = xr[j];
      ssq += v.x * v.x + v.y * v.y + v.z * v.z + v.w * v.w;
      const int c0 = s * 8 + j * 4;
      xs[c0 + 0][r] = v.x; xs[c0 + 1][r] = v.y;
      xs[c0 + 2][r] = v.z; xs[c0 + 3][r] = v.w;
    }
    {
      float4 v = wr;
      wls[wsg * 4 + 0][wk] = v.x; wls[wsg * 4 + 1][wk] = v.y;
      wls[wsg * 4 + 2][wk] = v.z; wls[wsg * 4 + 3][wk] = v.w;
    }
    if (ch < 15) {   // prefetch next chunk (in flight during compute)
      xr[0] = xrow[(ch + 1) * 4 + s * 2];
      xr[1] = xrow[(ch + 1) * 4 + s * 2 + 1];
      wr = wrow[(ch + 1) * 4 + wsg];
    }
    __syncthreads();

#pragma unroll 4
    for (int cl = 0; cl < 16; ++cl) {
      float xv[8];
#pragma unroll
      for (int i = 0; i < 8; ++i) xv[i] = xs[cl][tg + 16 * i];
      float4 wv = *reinterpret_cast<const float4*>(&wls[cl][kg * 4]);
#pragma unroll
      for (int i = 0; i < 8; ++i) {
        acc[i][0] = fmaf(xv[i], wv.x, acc[i][0]);
        acc[i][1] = fmaf(xv[i], wv.y, acc[i][1]);
        acc[i][2] = fmaf(xv[i], wv.z, acc[i][2]);
        acc[i][3] = fmaf(xv[i], wv.w, acc[i][3]);
      }
    }
  }

  // per-token inverse norm (row split over 2 adjacent lanes)
  ssq += __shfl_xor(ssq, 1);
  if (s == 0) invls[r] = 1.0f / fmaxf(sqrtf(ssq), 1e-12f);
  __syncthreads();
  if (tid < 128) invn[(size_t)b * NN + n0 + tid] = invls[tid];

  float inv_t[8], M[8];
#pragma unroll
  for (int i = 0; i < 8; ++i) inv_t[i] = invls[tg + 16 * i];
#pragma unroll
  for (int i = 0; i < 8; ++i) {
    float m = -3.4e38f;
#pragma unroll
    for (int j = 0; j < 4; ++j) {
      acc[i][j] *= inv_t[i];
      m = fmaxf(m, acc[i][j]);
    }
    mxb[kg][tg + 16 * i] = m;
  }
  __syncthreads();
#pragma unroll
  for (int i = 0; i < 8; ++i) {
    const int t = tg + 16 * i;
    float m = mxb[0][t];
#pragma unroll
    for (int kk = 1; kk < 16; ++kk) m = fmaxf(m, mxb[kk][t]);
    M[i] = m;
  }
#pragma unroll
  for (int i = 0; i < 8; ++i) {
    float sl = 0.f;
#pragma unroll
    for (int j = 0; j < 4; ++j) {
      acc[i][j] = __expf(acc[i][j] - M[i]);
      sl += acc[i][j];
    }
    smb[kg][tg + 16 * i] = sl;
  }
  __syncthreads();
#pragma unroll
  for (int i = 0; i < 8; ++i) {
    const int t = tg + 16 * i;
    float sl = smb[0][t];
#pragma unroll
    for (int kk = 1; kk < 16; ++kk) sl += smb[kk][t];
    const float rs = 1.0f / sl;
#pragma unroll
    for (int j = 0; j < 4; ++j) acc[i][j] *= rs;
  }
#pragma unroll
  for (int j = 0; j < 4; ++j) {
    float* dst = sa + ((size_t)b * KK + kg * 4 + j) * NN + n0 + tg;
#pragma unroll
    for (int i = 0; i < 8; ++i) dst[16 * i] = acc[i][j];
  }
}

// ============================================================
// K3: vlad partial GEMM (round-4, measured-good)
// ============================================================
__global__ __launch_bounds__(256) void k_vlad(
    const float* __restrict__ x, const float* __restrict__ sa,
    const float* __restrict__ invn, float* __restrict__ vpart,
    float* __restrict__ spart) {
  __shared__ __align__(16) float xs[32][260];  // [n][c]
  __shared__ __align__(16) float ss[32][68];   // [n][k]

  const int tid = threadIdx.x;
  const int ch = blockIdx.x;     // 0..15
  const int b  = blockIdx.y;     // 0..31
  const int cg = tid & 31;       // c-group
  const int kg = tid >> 5;       // k-group 0..7
  const int lnn = tid >> 3;      // load row 0..31
  const int lseg = tid & 7;      // 0..7

  float acc[8][8];
#pragma unroll
  for (int i = 0; i < 8; ++i)
#pragma unroll
    for (int j = 0; j < 8; ++j) acc[i][j] = 0.f;
  float ssum[8];
#pragma unroll
  for (int i = 0; i < 8; ++i) ssum[i] = 0.f;

  for (int tile = 0; tile < 8; ++tile) {
    const int nb = ch * 256 + tile * 32;

    const float invv = invn[b * NN + nb + lnn];
    const float4* xr = reinterpret_cast<const float4*>(
        x + ((size_t)b * NN + nb + lnn) * CC);
    float4 v4[8];
#pragma unroll
    for (int j = 0; j < 8; ++j) v4[j] = xr[lseg + 8 * j];
    float sv8[8];
#pragma unroll
    for (int kk = 0; kk < 8; ++kk)
      sv8[kk] = sa[((size_t)b * KK + kg * 8 + kk) * NN + nb + (tid & 31)];

    __syncthreads();

#pragma unroll
    for (int j = 0; j < 8; ++j) {
      float4 v = v4[j];
      v.x *= invv; v.y *= invv; v.z *= invv; v.w *= invv;
      *reinterpret_cast<float4*>(&xs[lnn][(lseg + 8 * j) * 4]) = v;
    }
#pragma unroll
    for (int kk = 0; kk < 8; ++kk) ss[tid & 31][kg * 8 + kk] = sv8[kk];
    __syncthreads();

#pragma unroll 2
    for (int n = 0; n < 32; ++n) {
      float4 s0 = *reinterpret_cast<const float4*>(&ss[n][kg * 8]);
      float4 s1 = *reinterpret_cast<const float4*>(&ss[n][kg * 8 + 4]);
      float4 x0 = *reinterpret_cast<const float4*>(&xs[n][cg * 8]);
      float4 x1 = *reinterpret_cast<const float4*>(&xs[n][cg * 8 + 4]);
      float sv[8] = {s0.x, s0.y, s0.z, s0.w, s1.x, s1.y, s1.z, s1.w};
      float xv[8] = {x0.x, x0.y, x0.z, x0.w, x1.x, x1.y, x1.z, x1.w};
#pragma unroll
      for (int i = 0; i < 8; ++i) {
#pragma unroll
        for (int j = 0; j < 8; ++j)
          acc[i][j] = fmaf(sv[i], xv[j], acc[i][j]);
        ssum[i] += sv[i];
      }
    }
  }

  const size_t obase = (((size_t)b * 16 + ch) * KK + kg * 8) * CC + cg * 8;
#pragma unroll
  for (int i = 0; i < 8; ++i) {
    float4 o0 = {acc[i][0], acc[i][1], acc[i][2], acc[i][3]};
    float4 o1 = {acc[i][4], acc[i][5], acc[i][6], acc[i][7]};
    *reinterpret_cast<float4*>(vpart + obase + (size_t)i * CC) = o0;
    *reinterpret_cast<float4*>(vpart + obase + (size_t)i * CC + 4) = o1;
  }
  if (cg == 0) {
#pragma unroll
    for (int i = 0; i < 8; ++i)
      spart[((size_t)b * 16 + ch) * KK + kg * 8 + i] = ssum[i];
  }
}

// ============================================================
// K4: reduce partials, subtract S*centroid, intra-norm, /8
// ============================================================
__global__ __launch_bounds__(256) void k_vladnorm(
    const float* __restrict__ vpart, const float* __restrict__ spart,
    const float* __restrict__ cent, float* __restrict__ vladn) {
  const int b = blockIdx.x >> 6, k = blockIdx.x & 63;
  const int c = threadIdx.x;
  float v = 0.f, S = 0.f;
#pragma unroll
  for (int ch = 0; ch < 16; ++ch) {
    v += vpart[(((size_t)b * 16 + ch) * KK + k) * CC + c];
    S += spart[((size_t)b * 16 + ch) * KK + k];
  }
  v -= S * cent[k * CC + c];

  float ssq = v * v;
#pragma unroll
  for (int off = 32; off >= 1; off >>= 1) ssq += __shfl_xor(ssq, off);
  __shared__ float w4[4];
  if ((threadIdx.x & 63) == 0) w4[threadIdx.x >> 6] = ssq;
  __syncthreads();
  const float tot = w4[0] + w4[1] + w4[2] + w4[3];
  const float sc = 0.125f / fmaxf(sqrtf(tot), 1e-12f);
  vladn[(size_t)b * (KK * CC) + k * CC + c] = v * sc;
}

// ============================================================
// K5: hidden GEMM partials. grid (128 islabs, 2 d-halves)
// ============================================================
__global__ __launch_bounds__(256) void k_hidden(
    const float* __restrict__ vladn, const float* __restrict__ hw,
    float* __restrict__ k5p) {
  const int islab = blockIdx.x;           // 0..127
  const int dh = blockIdx.y;              // 0..1
  const int tid = threadIdx.x;
  const int d = dh * 128 + (tid & 127);
  const int ig = tid >> 7;
  const int ibase = islab * 128 + ig * 64;
  const int p = islab * 2 + ig;

  float w[64];
#pragma unroll 8
  for (int ii = 0; ii < 64; ++ii)
    w[ii] = hw[(size_t)(ibase + ii) * DD + d];

#pragma unroll 4
  for (int b2 = 0; b2 < 32; ++b2) {
    const float4* vp = reinterpret_cast<const float4*>(
        vladn + (size_t)b2 * (KK * CC) + ibase);
    float a = 0.f;
#pragma unroll
    for (int q = 0; q < 16; ++q) {
      float4 v = vp[q];
      a = fmaf(v.x, w[q * 4 + 0], a);
      a = fmaf(v.y, w[q * 4 + 1], a);
      a = fmaf(v.z, w[q * 4 + 2], a);
      a = fmaf(v.w, w[q * 4 + 3], a);
    }
    k5p[((size_t)p * 32 + b2) * DD + d] = a;
  }
}

// ============================================================
// K6: reduce 256 hidden partials -> o1p[8][32][256]
// ============================================================
__global__ __launch_bounds__(256) void k_red1(
    const float* __restrict__ k5p, float* __restrict__ o1p) {
  const int b = blockIdx.x & 31, ch = blockIdx.x >> 5, d = threadIdx.x;
  float s = 0.f;
#pragma unroll 4
  for (int p = ch * 32; p < ch * 32 + 32; ++p)
    s += k5p[((size_t)p * 32 + b) * DD + d];
  o1p[((size_t)ch * 32 + b) * DD + d] = s;
}

// ============================================================
// K7a: BN1 -> gating GEMM -> z.  grid 8 blocks, coalesced gw.
// block: 32 d2-cols x 8 b-groups (4 b each)
// ============================================================
__global__ __launch_bounds__(256) void k_final_a(
    const float* __restrict__ o1p, const float* __restrict__ gw,
    const float* __restrict__ bn2g, const float* __restrict__ bn2b,
    float* __restrict__ z) {
  __shared__ float yls[32][257];
  const int tid = threadIdx.x;

  {  // stage 1: y = BN1(out1), all 256 dims (redundant per block)
    const int d = tid;
    float vals[32];
    float m = 0.f;
#pragma unroll
    for (int b5 = 0; b5 < 32; ++b5) {
      float v = 0.f;
#pragma unroll
      for (int c2 = 0; c2 < 8; ++c2) v += o1p[((size_t)c2 * 32 + b5) * DD + d];
      vals[b5] = v; m += v;
    }
    m *= (1.f / 32.f);
    float var = 0.f;
#pragma unroll
    for (int b5 = 0; b5 < 32; ++b5) { float tt = vals[b5] - m; var += tt * tt; }
    var *= (1.f / 32.f);
    const float sc = bn2g[d] / sqrtf(var + 1e-5f);
    const float sh = bn2b[d];
#pragma unroll
    for (int b5 = 0; b5 < 32; ++b5) yls[b5][d] = (vals[b5] - m) * sc + sh;
  }
  __syncthreads();

  // stage 2: z[b][d2] = y[b] . gw[:,d2]
  const int d2l = tid & 31, bg = tid >> 5;
  const int d2 = blockIdx.x * 32 + d2l;
  float a4[4] = {0.f, 0.f, 0.f, 0.f};
  for (int dd = 0; dd < 256; ++dd) {
    const float w = gw[(size_t)dd * DD + d2];
#pragma unroll
    for (int bb = 0; bb < 4; ++bb)
      a4[bb] = fmaf(yls[bg * 4 + bb][dd], w, a4[bb]);
  }
#pragma unroll
  for (int bb = 0; bb < 4; ++bb)
    z[(size_t)(bg * 4 + bb) * DD + d2] = a4[bb];
}

// ============================================================
// K7b: BN2(z) -> sigmoid -> gate*y -> out.  grid 1 block, d2 = tid.
// ============================================================
__global__ __launch_bounds__(256) void k_final_b(
    const float* __restrict__ o1p, const float* __restrict__ z,
    const float* __restrict__ bn2g, const float* __restrict__ bn2b,
    const float* __restrict__ gbng, const float* __restrict__ gbnb,
    float* __restrict__ out) {
  const int d = threadIdx.x;

  // BN2 stats over batch of z[:,d]
  float zv[32];
  float m2 = 0.f;
#pragma unroll
  for (int b5 = 0; b5 < 32; ++b5) { zv[b5] = z[(size_t)b5 * DD + d]; m2 += zv[b5]; }
  m2 *= (1.f / 32.f);
  float v2 = 0.f;
#pragma unroll
  for (int b5 = 0; b5 < 32; ++b5) { float tt = zv[b5] - m2; v2 += tt * tt; }
  v2 *= (1.f / 32.f);
  const float sc2 = gbng[d] / sqrtf(v2 + 1e-5f);
  const float sh2 = gbnb[d];

  // recompute y[:,d] = BN1(out1)[:,d]
  float vals[32];
  float m = 0.f;
#pragma unroll
  for (int b5 = 0; b5 < 32; ++b5) {
    float v = 0.f;
#pragma unroll
    for (int c2 = 0; c2 < 8; ++c2) v += o1p[((size_t)c2 * 32 + b5) * DD + d];
    vals[b5] = v; m += v;
  }
  m *= (1.f / 32.f);
  float var = 0.f;
#pragma unroll
  for (int b5 = 0; b5 < 32; ++b5) { float tt = vals[b5] - m; var += tt * tt; }
  var *= (1.f / 32.f);
  const float sc1 = bn2g[d] / sqrtf(var + 1e-5f);
  const float sh1 = bn2b[d];

#pragma unroll
  for (int b5 = 0; b5 < 32; ++b5) {
    const float y = (vals[b5] - m) * sc1 + sh1;
    const float gn = (zv[b5] - m2) * sc2 + sh2;
    const float gate = 1.f / (1.f + __expf(-gn));
    out[(size_t)b5 * DD + d] = y * gate;
  }
}

// ============================================================
extern "C" void kernel_launch(void* const* d_in, const int* in_sizes, int n_in,
                              void* d_out, int out_size, void* d_ws, size_t ws_size,
                              hipStream_t stream) {
  const float* x      = (const float*)d_in[0];
  const float* conv_w = (const float*)d_in[1];
  const float* cent   = (const float*)d_in[2];
  const float* hw     = (const float*)d_in[3];
  const float* gw     = (const float*)d_in[4];
  const float* bn2g   = (const float*)d_in[5];
  const float* bn2b   = (const float*)d_in[6];
  const float* gbng   = (const float*)d_in[7];
  const float* gbnb   = (const float*)d_in[8];

  float* ws    = (float*)d_ws;
  float* sa    = ws + SA_OFF;
  float* invn  = ws + INV_OFF;
  float* vpart = ws + VP_OFF;
  float* spart = ws + SP_OFF;
  float* vladn = ws + VN_OFF;
  float* o1p   = ws + O1P_OFF;
  float* k5p   = ws + K5_OFF;
  float* z     = ws + Z_OFF;

  k_softmax<<<BB * (NN / 128), 256, 0, stream>>>(x, conv_w, sa, invn);
  k_vlad<<<dim3(16, BB), 256, 0, stream>>>(x, sa, invn, vpart, spart);
  k_vladnorm<<<BB * KK, 256, 0, stream>>>(vpart, spart, cent, vladn);
  k_hidden<<<dim3(128, 2), 256, 0, stream>>>(vladn, hw, k5p);
  k_red1<<<256, 256, 0, stream>>>(k5p, o1p);
  k_final_a<<<8, 256, 0, stream>>>(o1p, gw, bn2g, bn2b, z);
  k_final_b<<<1, 256, 0, stream>>>(o1p, z, bn2g, bn2b, gbng, gbnb,
                                   (float*)d_out);
}